// Round 1
// baseline (2351.724 us; speedup 1.0000x reference)
//
#include <hip/hip_runtime.h>
#include <hip/hip_bf16.h>

using bf16 = __hip_bfloat16;

static __device__ __forceinline__ float b2f(bf16 v) { return __bfloat162float(v); }
static __device__ __forceinline__ bf16  f2b(float v) { return __float2bfloat16(v); }

// ---------------------------------------------------------------------------
// Binarize: wb[i] = w[i] >= 0 ? +1 : -1   (straight-through forward value)
// ---------------------------------------------------------------------------
__global__ void binarize_kernel(const float* __restrict__ w,
                                float* __restrict__ wb, int n) {
    int i = blockIdx.x * 256 + threadIdx.x;
    if (i < n) wb[i] = (w[i] >= 0.f) ? 1.f : -1.f;
}

// ---------------------------------------------------------------------------
// conv1 (1->128, 3x3, VALID) + bias + leaky(0.5) + maxpool2, fused.
// x: [32,1,224,224] f32 -> a1: [32,128,111,111] bf16
// One thread per pooled output pixel; computes the 2x2 conv window.
// ---------------------------------------------------------------------------
__global__ __launch_bounds__(256) void conv1_kernel(
    const float* __restrict__ x, const float* __restrict__ w1b,
    const float* __restrict__ b1, bf16* __restrict__ a1) {
    const int b = blockIdx.z, c = blockIdx.y;
    int p = blockIdx.x * 256 + threadIdx.x;
    if (p >= 111 * 111) return;
    int ph = p / 111, pw = p % 111;

    float s[9];
#pragma unroll
    for (int k = 0; k < 9; ++k) s[k] = w1b[c * 9 + k];
    const float bias = b1[c];

    const float* xp = x + (size_t)b * 224 * 224;
    const int h0 = 2 * ph, w0 = 2 * pw;
    float win[4][4];
#pragma unroll
    for (int i = 0; i < 4; ++i)
#pragma unroll
        for (int j = 0; j < 4; ++j)
            win[i][j] = xp[(h0 + i) * 224 + (w0 + j)];

    float m = -1e30f;
#pragma unroll
    for (int i = 0; i < 2; ++i)
#pragma unroll
        for (int j = 0; j < 2; ++j) {
            float acc = bias;
#pragma unroll
            for (int kh = 0; kh < 3; ++kh)
#pragma unroll
                for (int kw = 0; kw < 3; ++kw)
                    acc += s[kh * 3 + kw] * win[i + kh][j + kw];
            acc = (acc >= 0.f) ? acc : 0.5f * acc;
            m = fmaxf(m, acc);
        }
    a1[((size_t)(b * 128 + c) * 111 + ph) * 111 + pw] = f2b(m);
}

// ---------------------------------------------------------------------------
// Generic conv3x3 (IC -> OC) + bias + leaky + maxpool2, LDS-tiled.
// Block: 256 threads = 4 waves; each wave owns 2 output channels,
// 64 lanes = 8x8 pooled-pixel tile (16x16 conv px, 18x18 input window).
// IC processed in chunks of ICCH staged into LDS (f32 after bf16 load).
// ---------------------------------------------------------------------------
template <int IC, int ICCH, int OCPB>
__global__ __launch_bounds__(256) void convpool_kernel(
    const bf16* __restrict__ in, const float* __restrict__ wb,
    const float* __restrict__ bias, bf16* __restrict__ out,
    int inH, int inW, int poolH, int poolW, int OC, int tilesX) {
    __shared__ float xt[ICCH][18 * 18];
    __shared__ float wt[OCPB][ICCH][12];  // [12] stride -> 16B-aligned rows

    const int b = blockIdx.z;
    const int ocb = blockIdx.y * OCPB;
    const int tpy = blockIdx.x / tilesX, tpx = blockIdx.x % tilesX;
    const int PH0 = tpy * 8, PW0 = tpx * 8;
    const int r0 = 2 * PH0, c0 = 2 * PW0;  // input-window origin

    const int tid = threadIdx.x;
    const int g = tid >> 6;      // wave id 0..3 -> oc pair
    const int s = tid & 63;
    const int lph = s >> 3, lpw = s & 7;

    float acc[2][2][2] = {};  // [oc][i][j]

    const int nchunks = IC / ICCH;
    for (int ch = 0; ch < nchunks; ++ch) {
        const int icb = ch * ICCH;
        __syncthreads();
        // stage input window 18x18 for ICCH channels (zero-pad OOB)
        for (int e = tid; e < ICCH * 18 * 18; e += 256) {
            int ic = e / (18 * 18);
            int rem = e % (18 * 18);
            int r = rem / 18, cl = rem % 18;
            int gr = r0 + r, gc = c0 + cl;
            float v = 0.f;
            if (gr < inH && gc < inW)
                v = b2f(in[(((size_t)b * IC + icb + ic) * inH + gr) * inW + gc]);
            xt[ic][rem] = v;
        }
        // stage weights [OCPB][ICCH][9]
        for (int e = tid; e < OCPB * ICCH * 9; e += 256) {
            int oc = e / (ICCH * 9);
            int rem = e % (ICCH * 9);
            int ic = rem / 9, k = rem % 9;
            wt[oc][ic][k] = wb[((size_t)(ocb + oc) * IC + icb + ic) * 9 + k];
        }
        __syncthreads();

        for (int ic = 0; ic < ICCH; ++ic) {
            float win[4][4];
#pragma unroll
            for (int r = 0; r < 4; ++r)
#pragma unroll
                for (int cc = 0; cc < 4; ++cc)
                    win[r][cc] = xt[ic][(2 * lph + r) * 18 + 2 * lpw + cc];
            float wA[9], wB[9];
#pragma unroll
            for (int k = 0; k < 9; ++k) {
                wA[k] = wt[g * 2 + 0][ic][k];
                wB[k] = wt[g * 2 + 1][ic][k];
            }
#pragma unroll
            for (int i = 0; i < 2; ++i)
#pragma unroll
                for (int j = 0; j < 2; ++j) {
                    float sA = 0.f, sB = 0.f;
#pragma unroll
                    for (int kh = 0; kh < 3; ++kh)
#pragma unroll
                        for (int kw = 0; kw < 3; ++kw) {
                            float xv = win[i + kh][j + kw];
                            sA += wA[kh * 3 + kw] * xv;
                            sB += wB[kh * 3 + kw] * xv;
                        }
                    acc[0][i][j] += sA;
                    acc[1][i][j] += sB;
                }
        }
    }

    const int ph = PH0 + lph, pw = PW0 + lpw;
    if (ph < poolH && pw < poolW) {
#pragma unroll
        for (int o = 0; o < 2; ++o) {
            int oc = ocb + g * 2 + o;
            float bi = bias[oc];
            float m = -1e30f;
#pragma unroll
            for (int i = 0; i < 2; ++i)
#pragma unroll
                for (int j = 0; j < 2; ++j) {
                    float v = acc[o][i][j] + bi;
                    v = (v >= 0.f) ? v : 0.5f * v;
                    m = fmaxf(m, v);
                }
            out[(((size_t)b * OC + oc) * poolH + ph) * poolW + pw] = f2b(m);
        }
    }
}

// ---------------------------------------------------------------------------
// conv4 (32->8, kernel 3x2, VALID) + bias, no activation/pool.
// a3: [32,32,26,26] bf16 -> out: [32, 8*24*25] f32 (flattened)
// ---------------------------------------------------------------------------
__global__ __launch_bounds__(256) void conv4_kernel(
    const bf16* __restrict__ a3, const float* __restrict__ wb,
    const float* __restrict__ b4, float* __restrict__ out) {
    int i = blockIdx.x * 256 + threadIdx.x;
    if (i >= 32 * 4800) return;
    int b = i / 4800;
    int rem = i % 4800;
    int oc = rem / 600;
    int r2 = rem % 600;
    int oh = r2 / 25, ow = r2 % 25;

    float acc = b4[oc];
    const bf16* xp = a3 + (size_t)b * 32 * 26 * 26;
    const float* wp = wb + oc * 32 * 6;
#pragma unroll 4
    for (int ic = 0; ic < 32; ++ic) {
#pragma unroll
        for (int kh = 0; kh < 3; ++kh)
#pragma unroll
            for (int kw = 0; kw < 2; ++kw)
                acc += wp[ic * 6 + kh * 2 + kw] *
                       b2f(xp[(ic * 26 + oh + kh) * 26 + ow + kw]);
    }
    out[i] = acc;
}

// ---------------------------------------------------------------------------
extern "C" void kernel_launch(void* const* d_in, const int* in_sizes, int n_in,
                              void* d_out, int out_size, void* d_ws, size_t ws_size,
                              hipStream_t stream) {
    const float* x  = (const float*)d_in[0];
    const float* w1 = (const float*)d_in[1];
    const float* b1 = (const float*)d_in[2];
    const float* w2 = (const float*)d_in[3];
    const float* b2 = (const float*)d_in[4];
    const float* w3 = (const float*)d_in[5];
    const float* b3 = (const float*)d_in[6];
    const float* w4 = (const float*)d_in[7];
    const float* b4 = (const float*)d_in[8];
    float* out = (float*)d_out;

    char* ws = (char*)d_ws;
    size_t off = 0;
    auto alloc = [&](size_t bytes) {
        void* p = ws + off;
        off = (off + bytes + 255) & ~(size_t)255;
        return p;
    };
    bf16* a1 = (bf16*)alloc((size_t)32 * 128 * 111 * 111 * 2);  // 100.9 MB
    bf16* a2 = (bf16*)alloc((size_t)32 * 64 * 54 * 54 * 2);     // 11.9 MB
    bf16* a3 = (bf16*)alloc((size_t)32 * 32 * 26 * 26 * 2);     // 1.4 MB
    float* w1b = (float*)alloc(1152 * 4);
    float* w2b = (float*)alloc(73728 * 4);
    float* w3b = (float*)alloc(18432 * 4);
    float* w4b = (float*)alloc(1536 * 4);

    binarize_kernel<<<dim3((1152 + 255) / 256), 256, 0, stream>>>(w1, w1b, 1152);
    binarize_kernel<<<dim3((73728 + 255) / 256), 256, 0, stream>>>(w2, w2b, 73728);
    binarize_kernel<<<dim3((18432 + 255) / 256), 256, 0, stream>>>(w3, w3b, 18432);
    binarize_kernel<<<dim3((1536 + 255) / 256), 256, 0, stream>>>(w4, w4b, 1536);

    // conv1 + leaky + pool : x -> a1 [32,128,111,111]
    dim3 g1((111 * 111 + 255) / 256, 128, 32);
    conv1_kernel<<<g1, 256, 0, stream>>>(x, w1b, b1, a1);

    // conv2 + leaky + pool : a1 -> a2 [32,64,54,54]
    dim3 g2(7 * 7, 64 / 8, 32);
    convpool_kernel<128, 32, 8><<<g2, 256, 0, stream>>>(
        a1, w2b, b2, a2, 111, 111, 54, 54, 64, 7);

    // conv3 + leaky + pool : a2 -> a3 [32,32,26,26]
    dim3 g3(4 * 4, 32 / 8, 32);
    convpool_kernel<64, 32, 8><<<g3, 256, 0, stream>>>(
        a2, w3b, b3, a3, 54, 54, 26, 26, 32, 4);

    // conv4 : a3 -> out [32,4800]
    conv4_kernel<<<dim3((32 * 4800 + 255) / 256), 256, 0, stream>>>(
        a3, w4b, b4, out);
}

// Round 2
// 656.760 us; speedup vs baseline: 3.5808x; 3.5808x over previous
//
#include <hip/hip_runtime.h>
#include <hip/hip_bf16.h>

using bf16 = __hip_bfloat16;
typedef short  short8 __attribute__((ext_vector_type(8)));   // 8 bf16 (4 VGPR)
typedef float  f32x4  __attribute__((ext_vector_type(4)));

static __device__ __forceinline__ float b2f(bf16 v) { return __bfloat162float(v); }
static __device__ __forceinline__ bf16  f2b(float v) { return __float2bfloat16(v); }

// ---------------------------------------------------------------------------
// Binarize + reorder weights.
// ---------------------------------------------------------------------------
// w1 [128][1][3][3] f32 -> w1t f32 [9][128]  (r-major, c contiguous)
__global__ void bin1_kernel(const float* __restrict__ w, float* __restrict__ o) {
    int i = blockIdx.x * 256 + threadIdx.x;
    if (i >= 128 * 9) return;
    int c = i / 9, r = i % 9;
    o[r * 128 + c] = (w[i] >= 0.f) ? 1.f : -1.f;
}
// w OIHW [OC][IC][3][3] -> wA bf16 [OC][9*IC] with k = r*IC + ic
__global__ void bin3x3_kernel(const float* __restrict__ w, bf16* __restrict__ o,
                              int OC, int IC) {
    int i = blockIdx.x * 256 + threadIdx.x;
    if (i >= OC * IC * 9) return;
    int oc = i / (IC * 9), rem = i % (IC * 9);
    int ic = rem / 9, r = rem % 9;
    o[oc * (IC * 9) + r * IC + ic] = f2b((w[i] >= 0.f) ? 1.f : -1.f);
}
// w4 [8][32][3][2] -> wc4 f32 [8][6][32]  (r = kh*2+kw, ic contiguous)
__global__ void bin4_kernel(const float* __restrict__ w, float* __restrict__ o) {
    int i = blockIdx.x * 256 + threadIdx.x;
    if (i >= 8 * 32 * 6) return;
    int oc = i / 192, rem = i % 192;
    int ic = rem / 6, r = rem % 6;
    o[oc * 192 + r * 32 + ic] = (w[i] >= 0.f) ? 1.f : -1.f;
}

// ---------------------------------------------------------------------------
// conv1 (1->128, 3x3) + bias + leaky + maxpool2.  x f32 NCHW -> a1 bf16 NHWC
// a1[b][ph][pw][c], 128 c contiguous.  Block 256: 2 pixels x 128 channels.
// ---------------------------------------------------------------------------
__global__ __launch_bounds__(256) void conv1_kernel(
    const float* __restrict__ x, const float* __restrict__ w1t,
    const float* __restrict__ b1, bf16* __restrict__ a1) {
    const int tid = threadIdx.x;
    const int c = tid & 127;
    const int p = blockIdx.x * 2 + (tid >> 7);
    if (p >= 111 * 111) return;
    const int b = blockIdx.y;
    const int ph = p / 111, pw = p % 111;

    float s[9];
#pragma unroll
    for (int k = 0; k < 9; ++k) s[k] = w1t[k * 128 + c];
    const float bias = b1[c];

    const float* xp = x + (size_t)b * 224 * 224;
    const int h0 = 2 * ph, w0 = 2 * pw;
    float win[4][4];
#pragma unroll
    for (int i = 0; i < 4; ++i)
#pragma unroll
        for (int j = 0; j < 4; ++j)
            win[i][j] = xp[(h0 + i) * 224 + (w0 + j)];

    float m = -1e30f;
#pragma unroll
    for (int i = 0; i < 2; ++i)
#pragma unroll
        for (int j = 0; j < 2; ++j) {
            float acc = bias;
#pragma unroll
            for (int kh = 0; kh < 3; ++kh)
#pragma unroll
                for (int kw = 0; kw < 3; ++kw)
                    acc += s[kh * 3 + kw] * win[i + kh][j + kw];
            acc = (acc >= 0.f) ? acc : 0.5f * acc;
            m = fmaxf(m, acc);
        }
    a1[((size_t)(b * 111 + ph) * 111 + pw) * 128 + c] = f2b(m);
}

// ---------------------------------------------------------------------------
// MFMA implicit-GEMM conv3x3 + bias + leaky + maxpool2.
// in: NHWC bf16 [b][IN][IN][IC], out: NHWC bf16 [b][POOL][POOL][OC].
// Block 256 = 4 waves; wave w computes conv row oh0+w, cols ow0..ow0+15,
// all OC channels (MT=OC/16 mfma tiles of 16x16x32 over K = 9*IC).
// Input window [6][18][IC] staged once in LDS, XOR-swizzled 16B slots.
// ---------------------------------------------------------------------------
template <int IC, int OC, int IN, int POOL>
__global__ __launch_bounds__(256) void convmfma_kernel(
    const bf16* __restrict__ in, const bf16* __restrict__ wA,
    const float* __restrict__ bias, bf16* __restrict__ out) {
    constexpr int K = 9 * IC;
    constexpr int MT = OC / 16;
    constexpr int WIN_C = 18;
    constexpr int SLOTS = IC / 8;              // 16B slots per (row,col)
    constexpr int STAGE_BYTES = 6 * WIN_C * IC * 2;
    constexpr int PLD_BYTES = 4 * OC * 9 * 4;
    constexpr int SMEM = STAGE_BYTES > PLD_BYTES ? STAGE_BYTES : PLD_BYTES;
    __shared__ __align__(16) char smem[SMEM];

    const int tid = threadIdx.x;
    const int bimg = blockIdx.z;
    const int oh0 = blockIdx.y * 4;            // conv-row base (even)
    const int ow0 = blockIdx.x * 16;           // conv-col base (even)

    // ---- stage input window [6][18][IC] -> LDS, swizzled ----
    {
        const bf16* src = in + ((size_t)bimg * IN + oh0) * IN * IC;
        for (int ci = tid; ci < 6 * WIN_C * SLOTS; ci += 256) {
            int slot = ci % SLOTS, rc = ci / SLOTS;
            int row = rc / WIN_C, col = rc % WIN_C;
            int gc = ow0 + col;
            f32x4 v = {0.f, 0.f, 0.f, 0.f};
            if (gc < IN)
                v = *(const f32x4*)(src + ((size_t)row * IN + gc) * IC + slot * 8);
            *(f32x4*)(smem + rc * (IC * 2) + ((slot ^ (col & 7)) << 4)) = v;
        }
    }
    __syncthreads();

    const int w  = tid >> 6;                   // wave id -> conv row offset
    const int l  = tid & 63;
    const int lc = l & 15;                     // N (pixel) lane / M row lane
    const int lk = l >> 4;                     // k-group

    f32x4 acc[MT];
#pragma unroll
    for (int m = 0; m < MT; ++m) acc[m] = (f32x4){0.f, 0.f, 0.f, 0.f};

    const short8* aptr = (const short8*)(wA + (size_t)lc * K + lk * 8);
    const short8* bptr = (const short8*)smem;

    int rr = 0;
#pragma unroll
    for (int kh = 0; kh < 3; ++kh) {
#pragma unroll
        for (int kw = 0; kw < 3; ++kw, ++rr) {
            const int row = w + kh;
            const int col = lc + kw;
            const int bbase = (row * WIN_C + col) * SLOTS;
            const int cx = col & 7;
#pragma unroll
            for (int cc = 0; cc < IC / 32; ++cc) {
                short8 bfrag = bptr[bbase + ((cc * 4 + lk) ^ cx)];
#pragma unroll
                for (int m = 0; m < MT; ++m) {
                    short8 afrag = aptr[(m * 16 * K + rr * IC + cc * 32) >> 3];
                    acc[m] = __builtin_amdgcn_mfma_f32_16x16x32_bf16(
                        afrag, bfrag, acc[m], 0, 0, 0);
                }
            }
        }
    }

    // ---- epilogue: bias + leaky + 2x2 maxpool ----
    __syncthreads();                            // done reading stage buffer
    float* pld = (float*)smem;                  // [4][OC][9]
#pragma unroll
    for (int m = 0; m < MT; ++m) {
#pragma unroll
        for (int j = 0; j < 4; ++j) {
            const int oc = m * 16 + lk * 4 + j;
            float v = acc[m][j] + bias[oc];
            v = (v >= 0.f) ? v : 0.5f * v;
            float vm = fmaxf(v, __shfl_xor(v, 1, 64));
            if ((lc & 1) == 0) pld[(w * OC + oc) * 9 + (lc >> 1)] = vm;
        }
    }
    __syncthreads();

    const int ph0 = blockIdx.y * 2, pw0 = blockIdx.x * 8;
    for (int e = tid; e < 16 * OC; e += 256) {
        int oc = e & (OC - 1);
        int t = e / OC;
        int pw8 = t & 7, rp = t >> 3;
        int pw = pw0 + pw8;
        if (pw < POOL) {
            float v = fmaxf(pld[((2 * rp) * OC + oc) * 9 + pw8],
                            pld[((2 * rp + 1) * OC + oc) * 9 + pw8]);
            out[((size_t)(bimg * POOL + ph0 + rp) * POOL + pw) * OC + oc] = f2b(v);
        }
    }
}

// ---------------------------------------------------------------------------
// conv4 (32->8, 3x2) + bias.  a3 NHWC bf16 [32][26][26][32] -> out f32 [32][4800]
// ---------------------------------------------------------------------------
__global__ __launch_bounds__(256) void conv4_kernel(
    const bf16* __restrict__ a3, const float* __restrict__ wc4,
    const float* __restrict__ b4, float* __restrict__ out) {
    int i = blockIdx.x * 256 + threadIdx.x;
    if (i >= 32 * 4800) return;
    int b = i / 4800;
    int rem = i % 4800;
    int oc = rem / 600;
    int r2 = rem % 600;
    int oh = r2 / 25, ow = r2 % 25;

    float acc = b4[oc];
    int rr = 0;
#pragma unroll
    for (int kh = 0; kh < 3; ++kh) {
#pragma unroll
        for (int kw = 0; kw < 2; ++kw, ++rr) {
            const bf16* xp = a3 + ((size_t)(b * 26 + oh + kh) * 26 + (ow + kw)) * 32;
            const float* wp = wc4 + oc * 192 + rr * 32;
            short8 x0 = *(const short8*)(xp);
            short8 x1 = *(const short8*)(xp + 8);
            short8 x2 = *(const short8*)(xp + 16);
            short8 x3 = *(const short8*)(xp + 24);
#pragma unroll
            for (int j = 0; j < 8; ++j) {
                union { short s; unsigned short u; } u0{x0[j]}, u1{x1[j]}, u2{x2[j]}, u3{x3[j]};
                acc += wp[j]      * __bfloat162float(__hip_bfloat16_raw{u0.u});
                acc += wp[8 + j]  * __bfloat162float(__hip_bfloat16_raw{u1.u});
                acc += wp[16 + j] * __bfloat162float(__hip_bfloat16_raw{u2.u});
                acc += wp[24 + j] * __bfloat162float(__hip_bfloat16_raw{u3.u});
            }
        }
    }
    out[i] = acc;
}

// ---------------------------------------------------------------------------
extern "C" void kernel_launch(void* const* d_in, const int* in_sizes, int n_in,
                              void* d_out, int out_size, void* d_ws, size_t ws_size,
                              hipStream_t stream) {
    const float* x  = (const float*)d_in[0];
    const float* w1 = (const float*)d_in[1];
    const float* b1 = (const float*)d_in[2];
    const float* w2 = (const float*)d_in[3];
    const float* b2 = (const float*)d_in[4];
    const float* w3 = (const float*)d_in[5];
    const float* b3 = (const float*)d_in[6];
    const float* w4 = (const float*)d_in[7];
    const float* b4 = (const float*)d_in[8];
    float* out = (float*)d_out;

    char* ws = (char*)d_ws;
    size_t off = 0;
    auto alloc = [&](size_t bytes) {
        void* p = ws + off;
        off = (off + bytes + 255) & ~(size_t)255;
        return p;
    };
    bf16* a1 = (bf16*)alloc((size_t)32 * 111 * 111 * 128 * 2);  // NHWC, 100.9 MB
    bf16* a2 = (bf16*)alloc((size_t)32 * 54 * 54 * 64 * 2);     // NHWC, 11.9 MB
    bf16* a3 = (bf16*)alloc((size_t)32 * 26 * 26 * 32 * 2);     // NHWC, 1.4 MB
    float* w1t = (float*)alloc(1152 * 4);
    bf16* wA2 = (bf16*)alloc(73728 * 2);
    bf16* wA3 = (bf16*)alloc(18432 * 2);
    float* wc4 = (float*)alloc(1536 * 4);

    bin1_kernel<<<dim3((1152 + 255) / 256), 256, 0, stream>>>(w1, w1t);
    bin3x3_kernel<<<dim3((73728 + 255) / 256), 256, 0, stream>>>(w2, wA2, 64, 128);
    bin3x3_kernel<<<dim3((18432 + 255) / 256), 256, 0, stream>>>(w3, wA3, 32, 64);
    bin4_kernel<<<dim3((1536 + 255) / 256), 256, 0, stream>>>(w4, wc4);

    // conv1: x -> a1 [32,111,111,128] NHWC
    dim3 g1((111 * 111 + 1) / 2, 32);
    conv1_kernel<<<g1, 256, 0, stream>>>(x, w1t, b1, a1);

    // conv2: a1 -> a2 [32,54,54,64] NHWC   (conv 109x109, rows 0..107 used)
    dim3 g2(7, 27, 32);
    convmfma_kernel<128, 64, 111, 54><<<g2, 256, 0, stream>>>(a1, wA2, b2, a2);

    // conv3: a2 -> a3 [32,26,26,32] NHWC   (conv 52x52)
    dim3 g3(4, 13, 32);
    convmfma_kernel<64, 32, 54, 26><<<g3, 256, 0, stream>>>(a2, wA3, b3, a3);

    // conv4: a3 -> out [32,4800] f32
    conv4_kernel<<<dim3((32 * 4800 + 255) / 256), 256, 0, stream>>>(
        a3, wc4, b4, out);
}

// Round 5
// 365.785 us; speedup vs baseline: 6.4293x; 1.7955x over previous
//
#include <hip/hip_runtime.h>
#include <hip/hip_bf16.h>

using bf16 = __hip_bfloat16;
typedef short  short8  __attribute__((ext_vector_type(8)));   // 8 bf16
typedef float  f32x4   __attribute__((ext_vector_type(4)));
typedef float  f32x16  __attribute__((ext_vector_type(16)));
typedef unsigned short us4 __attribute__((ext_vector_type(4)));

static __device__ __forceinline__ float b2f(bf16 v) { return __bfloat162float(v); }
static __device__ __forceinline__ bf16  f2b(float v) { return __float2bfloat16(v); }
static __device__ __forceinline__ unsigned short f2bu(float v) {
    bf16 t = __float2bfloat16(v);
    return *(unsigned short*)&t;
}

// ---------------------------------------------------------------------------
// w1 [128][1][3][3] f32 -> w1t f32 [9][128]
__global__ void bin1_kernel(const float* __restrict__ w, float* __restrict__ o) {
    int i = blockIdx.x * 256 + threadIdx.x;
    if (i >= 128 * 9) return;
    int c = i / 9, r = i % 9;
    o[r * 128 + c] = (w[i] >= 0.f) ? 1.f : -1.f;
}

// Pack binarized OIHW weights into 32x32x16 MFMA A-fragment order:
// frag f = (mt*9 + r)*(IC/16) + cc ; lane l holds oc = mt*32+(l&31),
// k-slice ic = cc*16 + (l>>5)*8 + j.
__global__ void pack32_kernel(const float* __restrict__ w, bf16* __restrict__ o,
                              int OC, int IC) {
    int i = blockIdx.x * 256 + threadIdx.x;
    if (i >= OC * IC * 9) return;
    int j = i & 7;
    int l = (i >> 3) & 63;
    int f = i >> 9;
    int ICD16 = IC >> 4;
    int cc = f % ICD16;
    int t  = f / ICD16;
    int r  = t % 9;
    int mt = t / 9;
    int oc = mt * 32 + (l & 31);
    int ic = cc * 16 + ((l >> 5) << 3) + j;
    o[i] = f2b((w[(oc * IC + ic) * 9 + r] >= 0.f) ? 1.f : -1.f);
}

// w4 [8][32][3][2] -> wc4 f32 [8][6][32]
__global__ void bin4_kernel(const float* __restrict__ w, float* __restrict__ o) {
    int i = blockIdx.x * 256 + threadIdx.x;
    if (i >= 8 * 32 * 6) return;
    int oc = i / 192, rem = i % 192;
    int ic = rem / 6, r = rem % 6;
    o[oc * 192 + r * 32 + ic] = (w[i] >= 0.f) ? 1.f : -1.f;
}

// ---------------------------------------------------------------------------
// conv1 (1->128) + bias + leaky + pool.  x f32 NCHW -> a1 bf16 NHWC.
// 256 thr = 128 c x 2 groups; each thread computes 4 pooled px of one row.
// ---------------------------------------------------------------------------
__global__ __launch_bounds__(256) void conv1_kernel(
    const float* __restrict__ x, const float* __restrict__ w1t,
    const float* __restrict__ b1, bf16* __restrict__ a1) {
    const int tid = threadIdx.x;
    const int c = tid & 127;
    const int b = blockIdx.y;
    int idx = blockIdx.x * 2 + (tid >> 7);
    if (idx >= 111 * 28) return;
    int ph = idx / 28, pwg = idx % 28;
    int pw0 = pwg * 4;

    float s[9];
#pragma unroll
    for (int k = 0; k < 9; ++k) s[k] = w1t[k * 128 + c];
    const float bias = b1[c];

    const float* xp = x + (size_t)b * 224 * 224 + (2 * ph) * 224 + 2 * pw0;
    float win[4][10];
#pragma unroll
    for (int r = 0; r < 4; ++r)
#pragma unroll
        for (int j = 0; j < 10; ++j)
            win[r][j] = (2 * pw0 + j < 224) ? xp[r * 224 + j] : 0.f;

#pragma unroll
    for (int p = 0; p < 4; ++p) {
        int pw = pw0 + p;
        if (pw < 111) {
            float m = -1e30f;
#pragma unroll
            for (int i = 0; i < 2; ++i)
#pragma unroll
                for (int jj = 0; jj < 2; ++jj) {
                    float acc = bias;
#pragma unroll
                    for (int kh = 0; kh < 3; ++kh)
#pragma unroll
                        for (int kw = 0; kw < 3; ++kw)
                            acc += s[kh * 3 + kw] * win[i + kh][2 * p + jj + kw];
                    acc = (acc >= 0.f) ? acc : 0.5f * acc;
                    m = fmaxf(m, acc);
                }
            a1[((size_t)(b * 111 + ph) * 111 + pw) * 128 + c] = f2b(m);
        }
    }
}

// ---------------------------------------------------------------------------
// MFMA 32x32x16 implicit-GEMM conv3x3 + bias + leaky + maxpool2.
// Block: 256 thr, tile 16x16 conv px; wave w: rows 4w..4w+3 (2 n-tiles of
// 2 rows x 16 cols), all OC (MT m-tiles of 32). IC chunked by 64 into LDS.
// ---------------------------------------------------------------------------
template <int IC, int OC, int IN, int POOL>
__global__ __launch_bounds__(256, 3) void convmfma_kernel(
    const bf16* __restrict__ in, const bf16* __restrict__ wAp,
    const float* __restrict__ bias, bf16* __restrict__ out) {
    constexpr int MT = OC / 32;
    constexpr int CHUNKS = IC / 64;
    constexpr int ICD16 = IC / 16;
    __shared__ __align__(16) char smem[18 * 18 * 128];  // 41472 B

    const int tid = threadIdx.x;
    const int b = blockIdx.z;
    const int oh0 = blockIdx.y * 16;
    const int ow0 = blockIdx.x * 16;

    const int w   = tid >> 6;
    const int l   = tid & 63;
    const int lc4 = l & 15;
    const int r2  = (l >> 4) & 1;
    const int hh  = l >> 5;

    f32x16 acc[MT][2];
#pragma unroll
    for (int mt = 0; mt < MT; ++mt)
#pragma unroll
        for (int nt = 0; nt < 2; ++nt)
#pragma unroll
            for (int q = 0; q < 16; ++q) acc[mt][nt][q] = 0.f;

    for (int chunk = 0; chunk < CHUNKS; ++chunk) {
        if (chunk) __syncthreads();
        // ---- stage window rows oh0..+17, cols ow0..+17, ic chunk*64..+63 ----
        {
            const bf16* src = in + ((size_t)b * IN * IN) * IC + chunk * 64;
            for (int u = tid; u < 18 * 18 * 8; u += 256) {
                int slot = u & 7, cell = u >> 3;
                int row = cell / 18, col = cell - row * 18;
                int gr = oh0 + row, gc = ow0 + col;
                f32x4 v = {0.f, 0.f, 0.f, 0.f};
                if (gr < IN && gc < IN)
                    v = *(const f32x4*)(src + ((size_t)gr * IN + gc) * IC + slot * 8);
                *(f32x4*)(smem + cell * 128 + ((slot ^ (col & 7)) << 4)) = v;
            }
        }
        __syncthreads();

        // ---- K-loop: 9 taps x 4 ic-slices of 16 ----
#pragma unroll
        for (int kh = 0; kh < 3; ++kh) {
#pragma unroll
            for (int kw = 0; kw < 3; ++kw) {
                const int r = kh * 3 + kw;
                const int wincol = lc4 + kw;
                const int cx = wincol & 7;
#pragma unroll
                for (int cc = 0; cc < 4; ++cc) {
                    short8 af[MT];
#pragma unroll
                    for (int mt = 0; mt < MT; ++mt)
                        af[mt] = ((const short8*)wAp)[
                            (((mt * 9 + r) * ICD16) + chunk * 4 + cc) * 64 + l];
                    const int slot = cc * 2 + hh;
                    short8 bfr[2];
#pragma unroll
                    for (int nt = 0; nt < 2; ++nt) {
                        int cell = (4 * w + 2 * nt + r2 + kh) * 18 + wincol;
                        bfr[nt] = *(const short8*)(
                            smem + cell * 128 + ((slot ^ cx) << 4));
                    }
#pragma unroll
                    for (int mt = 0; mt < MT; ++mt)
#pragma unroll
                        for (int nt = 0; nt < 2; ++nt)
                            acc[mt][nt] = __builtin_amdgcn_mfma_f32_32x32x16_bf16(
                                af[mt], bfr[nt], acc[mt][nt], 0, 0, 0);
                }
            }
        }
    }

    // ---- epilogue: bias + leaky + 2x2 pool (rows at lane^16, cols lane^1) ----
    const bool wr = ((l & 17) == 0);
    const int pw = blockIdx.x * 8 + (lc4 >> 1);
#pragma unroll
    for (int mt = 0; mt < MT; ++mt) {
#pragma unroll
        for (int nt = 0; nt < 2; ++nt) {
            const int ph = blockIdx.y * 8 + 2 * w + nt;
#pragma unroll
            for (int g = 0; g < 4; ++g) {
                us4 o;
#pragma unroll
                for (int q2 = 0; q2 < 4; ++q2) {
                    int q = g * 4 + q2;
                    int oc = mt * 32 + 8 * g + 4 * hh + q2;
                    float v = acc[mt][nt][q] + bias[oc];
                    v = (v >= 0.f) ? v : 0.5f * v;
                    float m1 = fmaxf(v, __shfl_xor(v, 1));
                    float m  = fmaxf(m1, __shfl_xor(m1, 16));
                    o[q2] = f2bu(m);
                }
                if (wr && ph < POOL && pw < POOL)
                    *(us4*)(&out[((size_t)(b * POOL + ph) * POOL + pw) * OC +
                                 mt * 32 + 8 * g + 4 * hh]) = o;
            }
        }
    }
}

// ---------------------------------------------------------------------------
// conv4 (32->8, 3x2) + bias.  a3 NHWC bf16 -> out f32 [32][4800]
// ---------------------------------------------------------------------------
__global__ __launch_bounds__(256) void conv4_kernel(
    const bf16* __restrict__ a3, const float* __restrict__ wc4,
    const float* __restrict__ b4, float* __restrict__ out) {
    int i = blockIdx.x * 256 + threadIdx.x;
    if (i >= 32 * 4800) return;
    int b = i / 4800;
    int rem = i % 4800;
    int oc = rem / 600;
    int r2 = rem % 600;
    int oh = r2 / 25, ow = r2 % 25;

    float acc = b4[oc];
    int rr = 0;
#pragma unroll
    for (int kh = 0; kh < 3; ++kh) {
#pragma unroll
        for (int kw = 0; kw < 2; ++kw, ++rr) {
            const bf16* xp = a3 + ((size_t)(b * 26 + oh + kh) * 26 + (ow + kw)) * 32;
            const float* wp = wc4 + oc * 192 + rr * 32;
            short8 x0 = *(const short8*)(xp);
            short8 x1 = *(const short8*)(xp + 8);
            short8 x2 = *(const short8*)(xp + 16);
            short8 x3 = *(const short8*)(xp + 24);
#pragma unroll
            for (int j = 0; j < 8; ++j) {
                union { short s; unsigned short u; } u0{x0[j]}, u1{x1[j]}, u2{x2[j]}, u3{x3[j]};
                acc += wp[j]      * __bfloat162float(__hip_bfloat16_raw{u0.u});
                acc += wp[8 + j]  * __bfloat162float(__hip_bfloat16_raw{u1.u});
                acc += wp[16 + j] * __bfloat162float(__hip_bfloat16_raw{u2.u});
                acc += wp[24 + j] * __bfloat162float(__hip_bfloat16_raw{u3.u});
            }
        }
    }
    out[i] = acc;
}

// ---------------------------------------------------------------------------
extern "C" void kernel_launch(void* const* d_in, const int* in_sizes, int n_in,
                              void* d_out, int out_size, void* d_ws, size_t ws_size,
                              hipStream_t stream) {
    const float* x  = (const float*)d_in[0];
    const float* w1 = (const float*)d_in[1];
    const float* b1 = (const float*)d_in[2];
    const float* w2 = (const float*)d_in[3];
    const float* b2 = (const float*)d_in[4];
    const float* w3 = (const float*)d_in[5];
    const float* b3 = (const float*)d_in[6];
    const float* w4 = (const float*)d_in[7];
    const float* b4 = (const float*)d_in[8];
    float* out = (float*)d_out;

    char* ws = (char*)d_ws;
    size_t off = 0;
    auto alloc = [&](size_t bytes) {
        void* p = ws + off;
        off = (off + bytes + 255) & ~(size_t)255;
        return p;
    };
    bf16* a1 = (bf16*)alloc((size_t)32 * 111 * 111 * 128 * 2);  // NHWC
    bf16* a2 = (bf16*)alloc((size_t)32 * 54 * 54 * 64 * 2);     // NHWC
    bf16* a3 = (bf16*)alloc((size_t)32 * 26 * 26 * 32 * 2);     // NHWC
    float* w1t = (float*)alloc(1152 * 4);
    bf16* wAp2 = (bf16*)alloc(73728 * 2);
    bf16* wAp3 = (bf16*)alloc(18432 * 2);
    float* wc4 = (float*)alloc(1536 * 4);

    bin1_kernel<<<dim3((1152 + 255) / 256), 256, 0, stream>>>(w1, w1t);
    pack32_kernel<<<dim3((73728 + 255) / 256), 256, 0, stream>>>(w2, wAp2, 64, 128);
    pack32_kernel<<<dim3((18432 + 255) / 256), 256, 0, stream>>>(w3, wAp3, 32, 64);
    bin4_kernel<<<dim3((1536 + 255) / 256), 256, 0, stream>>>(w4, wc4);

    // conv1: x -> a1 [32,111,111,128]
    dim3 g1((111 * 28 + 1) / 2, 32);
    conv1_kernel<<<g1, 256, 0, stream>>>(x, w1t, b1, a1);

    // conv2: a1 -> a2 [32,54,54,64]  (conv extent 108x108)
    dim3 g2(7, 7, 32);
    convmfma_kernel<128, 64, 111, 54><<<g2, 256, 0, stream>>>(a1, wAp2, b2, a2);

    // conv3: a2 -> a3 [32,26,26,32]  (conv extent 52x52)
    dim3 g3(4, 4, 32);
    convmfma_kernel<64, 32, 54, 26><<<g3, 256, 0, stream>>>(a2, wAp3, b3, a3);

    // conv4: a3 -> out [32,4800]
    conv4_kernel<<<dim3((32 * 4800 + 255) / 256), 256, 0, stream>>>(
        a3, wc4, b4, out);
}